// Round 1
// baseline (622.592 us; speedup 1.0000x reference)
//
#include <hip/hip_runtime.h>
#include <hip/hip_bf16.h>

typedef unsigned short u16;
typedef unsigned int u32;
typedef __attribute__((ext_vector_type(8))) short short8;
typedef __attribute__((ext_vector_type(4))) float f32x4;

#define BATCH 8192
#define FEAT 512
#define DEG 32

__device__ __forceinline__ u16 f2b(float f){
  __hip_bfloat16 h = __float2bfloat16(f);
  return *reinterpret_cast<u16*>(&h);
}
__device__ __forceinline__ u32 pack2(float lo, float hi){
  return (u32)f2b(lo) | (((u32)f2b(hi)) << 16);
}

__device__ __forceinline__ f32x4 mfma_bf16_16x16x32(short8 a, short8 b, f32x4 c){
  asm("v_mfma_f32_16x16x32_bf16 %0, %1, %2, %0" : "+v"(c) : "v"(a), "v"(b));
  return c;
}

// async global->LDS, 16B per lane; LDS dest = wave-uniform base + lane*16
__device__ __forceinline__ void gload16(const u16* g, u16* l){
  __builtin_amdgcn_global_load_lds(
      (const __attribute__((address_space(1))) u32*)(const void*)g,
      (__attribute__((address_space(3))) u32*)(void*)l, 16, 0, 0);
}

// ---- gather + mean-pool: agg(f32), cat=[self|agg](bf16), env(bf16) ----
// float4 path: 2 batch rows per block, 16B/lane loads (G13)
__global__ __launch_bounds__(256) void gather_agg(
    const float* __restrict__ feat, const int* __restrict__ nidx,
    float* __restrict__ out_agg, u16* __restrict__ cat_bf, u16* __restrict__ env_bf)
{
  const int t = threadIdx.x;
  const int half = t >> 7, tl = t & 127;
  const int b = blockIdx.x * 2 + half;
  __shared__ int idx[2][DEG];
  if (t < 2 * DEG)
    idx[t >> 5][t & 31] = nidx[(size_t)(blockIdx.x * 2 + (t >> 5)) * DEG + (t & 31)];
  __syncthreads();
  const int f = tl * 4;
  // neigh_idx[:,0] == nodes (self), so row k=0 doubles as the self row
  const float4 sv = *(const float4*)(feat + (size_t)idx[half][0] * FEAT + f);
  float4 s = sv;
  #pragma unroll 8
  for (int k = 1; k < DEG; ++k){
    const float4 v = *(const float4*)(feat + (size_t)idx[half][k] * FEAT + f);
    s.x += v.x; s.y += v.y; s.z += v.z; s.w += v.w;
  }
  const float4 a = make_float4(s.x*(1.f/32.f), s.y*(1.f/32.f), s.z*(1.f/32.f), s.w*(1.f/32.f));
  const float4 e = make_float4((s.x-sv.x)*(1.f/31.f), (s.y-sv.y)*(1.f/31.f),
                               (s.z-sv.z)*(1.f/31.f), (s.w-sv.w)*(1.f/31.f));
  *(float4*)(out_agg + (size_t)b * FEAT + f) = a;
  *(uint2*)(cat_bf + (size_t)b * 1024 + f)        = make_uint2(pack2(sv.x, sv.y), pack2(sv.z, sv.w));
  *(uint2*)(cat_bf + (size_t)b * 1024 + FEAT + f) = make_uint2(pack2(a.x, a.y), pack2(a.z, a.w));
  *(uint2*)(env_bf + (size_t)b * FEAT + f)        = make_uint2(pack2(e.x, e.y), pack2(e.z, e.w));
}

// ---------------- f32 -> bf16 transpose (out[c][r] = bf16(in[r][c])) --------
__global__ __launch_bounds__(256) void transpose_f2b(
    const float* __restrict__ in, u16* __restrict__ out, int R, int C)
{
  __shared__ float tile[32][33];
  const int c0 = blockIdx.x * 32, r0 = blockIdx.y * 32;
  const int x = threadIdx.x, y = threadIdx.y;
  #pragma unroll
  for (int i = 0; i < 32; i += 8)
    tile[y + i][x] = in[(size_t)(r0 + y + i) * C + (c0 + x)];
  __syncthreads();
  #pragma unroll
  for (int i = 0; i < 32; i += 8)
    out[(size_t)(c0 + y + i) * R + (r0 + x)] = f2b(tile[x][y + i]);
}

// ---- 8-phase-class pipelined GEMM core: 256x256 tile, BK=32, tri-buffer ----
// 8 waves (2M x 4N), wave tile 128x64. Counted vmcnt(4) (never 0 mid-loop),
// T2 XOR swizzle (pre-swizzled global src + swizzled ds_read, linear LDS dest),
// T5 setprio around 16-MFMA clusters, raw s_barrier (no implicit vmcnt drain).
template<bool WRITE_RAW>
__device__ __forceinline__ void gemm_body8(
    const u16* __restrict__ A, int lda, const u16* __restrict__ BT, int ldb,
    int K, float* __restrict__ Craw, float* __restrict__ Crelu, int ldc,
    int m0, int n0, u16* __restrict__ As, u16* __restrict__ Bs)
{
  const int tid = threadIdx.x;
  const int wave = tid >> 6, lane = tid & 63;
  const int wr = wave >> 2, wc = wave & 3;           // 2M x 4N
  const int lm = lane & 15, quad = lane >> 4;

  // staging: thread covers row r0 (unit0) / r0+128 (unit1), physical chunk tid&3,
  // fetching the swizzled logical chunk so that reads can XOR-deswizzle.
  const int r0 = tid >> 2;
  const int csrc = ((tid & 3) ^ ((r0 >> 1) & 3)) * 8;
  const u16* aS = A  + (size_t)(m0 + r0) * lda + csrc;
  const u16* bS = BT + (size_t)(n0 + r0) * ldb + csrc;
  const size_t aU1 = (size_t)128 * lda, bU1 = (size_t)128 * ldb;
  u16* dA = As + tid * 8;            // + buf*8192 + unit*4096
  u16* dB = Bs + tid * 8;

  // swizzled read base: logical (row, quad) lives at physical chunk quad^((row>>1)&3)
  const int cs8 = (quad ^ ((lm >> 1) & 3)) * 8;
  const u16* rA = As + (wr * 128 + lm) * 32 + cs8;   // + cur*8192 + i*512
  const u16* rB = Bs + (wc * 64  + lm) * 32 + cs8;   // + cur*8192 + j*512

  f32x4 acc[8][4] = {};

  const int nt = K >> 5;             // BK = 32
  // ---- prologue: stage K-tiles 0 (buf0) and 1 (buf1); keep K1 in flight ----
  gload16(aS,            dA);
  gload16(aS + aU1,      dA + 4096);
  gload16(bS,            dB);
  gload16(bS + bU1,      dB + 4096);
  gload16(aS + 32,       dA + 8192);
  gload16(aS + 32 + aU1, dA + 8192 + 4096);
  gload16(bS + 32,       dB + 8192);
  gload16(bS + 32 + bU1, dB + 8192 + 4096);
  asm volatile("s_waitcnt vmcnt(4)" ::: "memory");   // K0 landed, K1's 4 in flight
  __builtin_amdgcn_s_barrier();

  int cur = 0, nxt = 2;
  int koff = 64;                                     // k-offset of tile t+2
  for (int t = 0; t < nt; ++t){
    const bool st = (t + 2) < nt;
    const u16* rAc = rA + cur * 8192;
    const u16* rBc = rB + cur * 8192;
    // ---------------- phase A: cols {0,1} ----------------
    short8 af[8], b0, b1;
    #pragma unroll
    for (int i = 0; i < 8; ++i) af[i] = *(const short8*)(rAc + i * 512);
    b0 = *(const short8*)(rBc);
    b1 = *(const short8*)(rBc + 512);
    if (st){
      gload16(aS + koff, dA + nxt * 8192);
      gload16(bS + koff, dB + nxt * 8192);
    }
    __builtin_amdgcn_s_barrier();
    asm volatile("s_waitcnt lgkmcnt(0)" ::: "memory");
    __builtin_amdgcn_sched_barrier(0);
    __builtin_amdgcn_s_setprio(1);
    #pragma unroll
    for (int i = 0; i < 8; ++i){
      acc[i][0] = mfma_bf16_16x16x32(af[i], b0, acc[i][0]);
      acc[i][1] = mfma_bf16_16x16x32(af[i], b1, acc[i][1]);
    }
    __builtin_amdgcn_s_setprio(0);
    __builtin_amdgcn_sched_barrier(0);
    __builtin_amdgcn_s_barrier();
    // ---------------- phase B: cols {2,3} ----------------
    short8 b2 = *(const short8*)(rBc + 1024);
    short8 b3 = *(const short8*)(rBc + 1536);
    if (st){
      gload16(aS + koff + aU1, dA + nxt * 8192 + 4096);
      gload16(bS + koff + bU1, dB + nxt * 8192 + 4096);
    }
    __builtin_amdgcn_s_barrier();
    asm volatile("s_waitcnt lgkmcnt(0)" ::: "memory");
    __builtin_amdgcn_sched_barrier(0);
    __builtin_amdgcn_s_setprio(1);
    #pragma unroll
    for (int i = 0; i < 8; ++i){
      acc[i][2] = mfma_bf16_16x16x32(af[i], b2, acc[i][2]);
      acc[i][3] = mfma_bf16_16x16x32(af[i], b3, acc[i][3]);
    }
    __builtin_amdgcn_s_setprio(0);
    // counted checkpoint: tile t+1 (read next iter) must be resident;
    // only this iter's 4 loads (tile t+2) may stay in flight.
    if (st) asm volatile("s_waitcnt vmcnt(4)" ::: "memory");
    else    asm volatile("s_waitcnt vmcnt(0)" ::: "memory");
    __builtin_amdgcn_sched_barrier(0);
    __builtin_amdgcn_s_barrier();
    koff += 32;
    cur = (cur == 2) ? 0 : cur + 1;
    nxt = (nxt == 2) ? 0 : nxt + 1;
  }

  // epilogue: C/D map col=lane&15, row=(lane>>4)*4+reg
  #pragma unroll
  for (int i = 0; i < 8; ++i){
    const int row = m0 + wr * 128 + i * 16 + quad * 4;
    #pragma unroll
    for (int j = 0; j < 4; ++j){
      const int col = n0 + wc * 64 + j * 16 + lm;
      #pragma unroll
      for (int r = 0; r < 4; ++r){
        const float v = acc[i][j][r];
        const size_t off = (size_t)(row + r) * ldc + col;
        if (WRITE_RAW) Craw[off] = v;
        Crelu[off] = fmaxf(v, 0.f);
      }
    }
  }
}

// GEMM1 (z=0): cat @ Wgen -> raw, gen.  GEMM2 (z=1): env @ Wgen[512:] -> envraw, envgen.
__global__ __launch_bounds__(512, 2) void gemm12(
    const u16* __restrict__ catA, const u16* __restrict__ envA,
    const u16* __restrict__ wgT,
    float* __restrict__ raw, float* __restrict__ gen,
    float* __restrict__ envraw, float* __restrict__ envgen)
{
  __shared__ __align__(16) u16 As[3 * 8192];
  __shared__ __align__(16) u16 Bs[3 * 8192];
  const int bid = blockIdx.x;                  // 256 blocks, 256%8==0
  const int wg = (bid & 7) * 32 + (bid >> 3);  // bijective XCD swizzle
  const int z = wg >> 7;
  const int r = wg & 127;
  const int m0 = (r >> 2) * 256;
  const int n0 = (r & 3) * 256;
  const u16* A  = z ? envA : catA;
  const int lda = z ? 512 : 1024;
  const int K   = z ? 512 : 1024;
  const u16* B  = z ? wgT + 512 : wgT;         // z=1: k-offset 512 into wgT rows
  float* Craw   = z ? envraw : raw;
  float* Crelu  = z ? envgen : gen;
  gemm_body8<true>(A, lda, B, 1024, K, Craw, Crelu, 1024, m0, n0, As, Bs);
}

// GEMM3: bnA @ weight1 -> relu only
__global__ __launch_bounds__(512, 2) void gemm3(
    const u16* __restrict__ bnA, const u16* __restrict__ w1T,
    float* __restrict__ to_out)
{
  __shared__ __align__(16) u16 As[3 * 8192];
  __shared__ __align__(16) u16 Bs[3 * 8192];
  const int bid = blockIdx.x;                  // 192 blocks, 192%8==0
  const int wg = (bid & 7) * 24 + (bid >> 3);
  const int m0 = (wg / 6) * 256;
  const int n0 = (wg % 6) * 256;
  gemm_body8<false>(bnA, 1536, w1T, 1536, 1536, nullptr, to_out, 1536, m0, n0, As, Bs);
}

// ---------------- BN stats: atomic-free slab partials ----------------
// grid (6, 8): block owns 256 cols (float4/thread), slab = 1024 rows
__global__ __launch_bounds__(256) void bn_partial(
    const float* __restrict__ agg, const float* __restrict__ gen,
    float* __restrict__ partials)
{
  const int tq = threadIdx.x & 63, ty = threadIdx.x >> 6;
  const int c = blockIdx.x * 256 + tq * 4;      // block-uniform branch below
  const int r0 = blockIdx.y * 1024;
  float4 s = make_float4(0.f,0.f,0.f,0.f), q = make_float4(0.f,0.f,0.f,0.f);
  if (c < 512){
    for (int r = r0 + ty; r < r0 + 1024; r += 4){
      const float4 x = *(const float4*)(agg + (size_t)r * 512 + c);
      s.x += x.x; s.y += x.y; s.z += x.z; s.w += x.w;
      q.x += x.x*x.x; q.y += x.y*x.y; q.z += x.z*x.z; q.w += x.w*x.w;
    }
  } else {
    for (int r = r0 + ty; r < r0 + 1024; r += 4){
      const float4 x = *(const float4*)(gen + (size_t)r * 1024 + (c - 512));
      s.x += x.x; s.y += x.y; s.z += x.z; s.w += x.w;
      q.x += x.x*x.x; q.y += x.y*x.y; q.z += x.z*x.z; q.w += x.w*x.w;
    }
  }
  __shared__ float4 sh[2][4][64];
  sh[0][ty][tq] = s; sh[1][ty][tq] = q;
  __syncthreads();
  if (ty == 0){
    float4 s0 = sh[0][0][tq], s1 = sh[0][1][tq], s2 = sh[0][2][tq], s3 = sh[0][3][tq];
    float4 q0 = sh[1][0][tq], q1 = sh[1][1][tq], q2 = sh[1][2][tq], q3 = sh[1][3][tq];
    const float4 S = make_float4(s0.x+s1.x+s2.x+s3.x, s0.y+s1.y+s2.y+s3.y,
                                 s0.z+s1.z+s2.z+s3.z, s0.w+s1.w+s2.w+s3.w);
    const float4 Q = make_float4(q0.x+q1.x+q2.x+q3.x, q0.y+q1.y+q2.y+q3.y,
                                 q0.z+q1.z+q2.z+q3.z, q0.w+q1.w+q2.w+q3.w);
    *(float4*)(partials + (size_t)blockIdx.y * 3072 + c)        = S;
    *(float4*)(partials + (size_t)blockIdx.y * 3072 + 1536 + c) = Q;
  }
}

__global__ __launch_bounds__(256) void bn_finalize(
    const float* __restrict__ partials, const float* __restrict__ gamma,
    const float* __restrict__ beta, float* __restrict__ sArr, float* __restrict__ tArr)
{
  const int c = blockIdx.x * 256 + threadIdx.x;
  if (c >= 1536) return;
  float s = 0.f, q = 0.f;
  #pragma unroll
  for (int k = 0; k < 8; ++k){
    s += partials[k * 3072 + c];
    q += partials[k * 3072 + 1536 + c];
  }
  const float mean = s * (1.f / 8192.f);
  const float var = q * (1.f / 8192.f) - mean * mean;
  const float rs = rsqrtf(var + 1e-5f);
  const float sc = gamma[c] * rs;
  sArr[c] = sc;
  tArr[c] = beta[c] - mean * sc;
}

// ---- materialize BN-folded GEMM3 A-matrix: bnA[m][c] = bf16(x*s + t) ----
__global__ __launch_bounds__(384) void prep_bnA(
    const float* __restrict__ agg, const float* __restrict__ gen,
    const float* __restrict__ sArr, const float* __restrict__ tArr,
    u16* __restrict__ bnA)
{
  const int m = blockIdx.x;
  const int t = threadIdx.x;       // 0..383
  const int c = t * 4;
  const float4 x = (c < 512)
      ? *(const float4*)(agg + (size_t)m * 512 + c)
      : *(const float4*)(gen + (size_t)m * 1024 + (c - 512));
  const float4 s4 = *(const float4*)(sArr + c);
  const float4 t4 = *(const float4*)(tArr + c);
  const u32 lo = pack2(fmaf(x.x, s4.x, t4.x), fmaf(x.y, s4.y, t4.y));
  const u32 hi = pack2(fmaf(x.z, s4.z, t4.z), fmaf(x.w, s4.w, t4.w));
  *(uint2*)(bnA + (size_t)m * 1536 + c) = make_uint2(lo, hi);
}

extern "C" void kernel_launch(void* const* d_in, const int* in_sizes, int n_in,
                              void* d_out, int out_size, void* d_ws, size_t ws_size,
                              hipStream_t stream)
{
  const float* feat  = (const float*)d_in[0];
  const float* Wgen  = (const float*)d_in[1];
  const float* W1    = (const float*)d_in[2];
  const float* gamma = (const float*)d_in[3];
  const float* beta  = (const float*)d_in[4];
  const int* nidx    = (const int*)d_in[6];

  float* o = (float*)d_out;
  float* out_agg    = o;                // [8192,512]
  float* out_to     = o + 4194304;      // [8192,1536]
  float* out_gen    = o + 16777216;     // [8192,1024]
  float* out_raw    = o + 25165824;     // [8192,1024]
  float* out_envgen = o + 33554432;     // [8192,1024]
  float* out_envraw = o + 41943040;     // [8192,1024]

  // ws: same 30.5 MB footprint as before; partials overlays wgT (dead after gemm12)
  char* w = (char*)d_ws;
  float* sArr = (float*)(w + 12288);         // 6,144 B
  float* tArr = (float*)(w + 18432);         // 6,144 B
  u16* wgT    = (u16*)(w + 32768);           // 2 MB    [1024,1024] bf16 W_gen^T
  float* partials = (float*)(w + 32768);     // 96 KB overlay (8 slabs x 3072)
  u16* w1T    = (u16*)(w + 2129920);         // 4.5 MB  [1536,1536] bf16 weight1^T
  u16* cat_bf = (u16*)(w + 6848512);         // 16.8 MB [8192,1024] bf16 [self|agg]
  u16* env_bf = (u16*)(w + 23625728);        // 8.4 MB  [8192,512]  bf16 env
  u16* bnA_bf = (u16*)(w + 6848512);         // 25.2 MB [8192,1536] overlay
  // end: 32,014,336 bytes

  gather_agg<<<BATCH / 2, 256, 0, stream>>>(feat, nidx, out_agg, cat_bf, env_bf);
  transpose_f2b<<<dim3(32, 32), dim3(32, 8), 0, stream>>>(Wgen, wgT, 1024, 1024);
  transpose_f2b<<<dim3(48, 48), dim3(32, 8), 0, stream>>>(W1, w1T, 1536, 1536);

  // GEMM1+GEMM2: 256 blocks (1/CU), 256^2 tiles, pipelined core
  gemm12<<<256, 512, 0, stream>>>(
      cat_bf, env_bf, wgT, out_raw, out_gen, out_envraw, out_envgen);

  bn_partial<<<dim3(6, 8), 256, 0, stream>>>(out_agg, out_gen, partials);
  bn_finalize<<<6, 256, 0, stream>>>(partials, gamma, beta, sArr, tArr);
  prep_bnA<<<BATCH, 384, 0, stream>>>(out_agg, out_gen, sArr, tArr, bnA_bf);

  gemm3<<<192, 512, 0, stream>>>(bnA_bf, w1T, out_to);
}